// Round 1
// baseline (4079.821 us; speedup 1.0000x reference)
//
#include <hip/hip_runtime.h>
#include <hip/hip_bf16.h>

// Problem constants (B,C,H,W) = (8,256,128,128), fp32 everywhere.
#define BB 8
#define CC 256
#define HH 128
#define WW 128
#define HW (HH*WW)        // 16384
#define NPIX (BB*HW)      // 131072

// ---------------------------------------------------------------------------
// conf = clip(1 - beta*sigmoid(20*sigmoid(x) - 4), 0, 1); also zero GN stats.
// ---------------------------------------------------------------------------
__global__ __launch_bounds__(256) void k_conf(const float* __restrict__ bl,
                                              const float* __restrict__ beta,
                                              float* __restrict__ conf,
                                              float* __restrict__ stats) {
  const int t = threadIdx.x;
  if (blockIdx.x == 0) { stats[t] = 0.f; stats[t + 256] = 0.f; }
  const int i = blockIdx.x * 256 + t;
  float x = bl[i];
  float s1 = 1.f / (1.f + expf(-x));
  float s2 = 1.f / (1.f + expf(-(20.f * s1 - 4.f)));
  float cv = 1.f - beta[0] * s2;
  conf[i] = fminf(fmaxf(cv, 0.f), 1.f);
}

// ---------------------------------------------------------------------------
// Transpose the 4 W_in matrices + out_w into [c_in][c_out] for coalesced
// weight streaming in the GEMM kernels. 5*65536 floats.
// ---------------------------------------------------------------------------
__global__ __launch_bounds__(256) void k_tr(const float* __restrict__ W_in,
                                            const float* __restrict__ out_w,
                                            float* __restrict__ wT) {
  const int i = blockIdx.x * 256 + threadIdx.x;   // 0 .. 5*65536
  const int m = i >> 16;
  const int rr = i & 65535;
  const int c = rr >> 8;
  const int d = rr & 255;
  const float* src = (m < 4) ? (W_in + m * 65536) : out_w;
  wT[i] = src[d * 256 + c];
}

// ---------------------------------------------------------------------------
// proj[dir] = W_in[dir] @ feature (per pixel) + b_in[dir]
// feature: [B][C][H][W] (channel-first). Output layout:
//   horizontal dirs: [B][H][W][C]   vertical dirs: [B][W][H][C]
// Block: 64 consecutive pixels of one image, 256 threads (thread = out chan).
// ---------------------------------------------------------------------------
__global__ __launch_bounds__(256) void k_proj_gemm(const float* __restrict__ feature,
                                                   const float* __restrict__ wT,
                                                   const float* __restrict__ bias,
                                                   float* __restrict__ proj,
                                                   int vertical) {
  __shared__ float Xs[64 * 256];   // [c][px], 64 KiB
  const int t = threadIdx.x;
  const int b = blockIdx.y;
  const int p0 = blockIdx.x * 64;

  // stage feature tile: row c is 64 contiguous floats -> coalesced
  {
    const int j = t & 63, c0 = t >> 6;
#pragma unroll
    for (int cc = 0; cc < 64; ++cc) {
      int c = cc * 4 + c0;
      Xs[c * 64 + j] = feature[((b * CC + c) << 14) + p0 + j];
    }
  }
  __syncthreads();

  const int d = t;
  float acc[64];
#pragma unroll
  for (int i = 0; i < 64; ++i) acc[i] = 0.f;

#pragma unroll 4
  for (int c = 0; c < 256; ++c) {
    float w = wT[c * 256 + d];                    // coalesced, L2-resident
#pragma unroll
    for (int p4 = 0; p4 < 16; ++p4) {
      float4 xv = *reinterpret_cast<const float4*>(&Xs[c * 64 + p4 * 4]);  // broadcast
      acc[p4 * 4 + 0] += w * xv.x;
      acc[p4 * 4 + 1] += w * xv.y;
      acc[p4 * 4 + 2] += w * xv.z;
      acc[p4 * 4 + 3] += w * xv.w;
    }
  }

  const float bia = bias[d];
#pragma unroll
  for (int jj = 0; jj < 64; ++jj) {
    int p = p0 + jj;
    int pos = vertical ? (((p & 127) << 7) + (p >> 7)) : p;   // w*H + h : h*W + w
    proj[(b * HW + pos) * 256 + d] = acc[jj] + bia;           // coalesced over d
  }
}

// ---------------------------------------------------------------------------
// Gated scan along the sequence dim.
//   h_l = relu(proj_l + g_l * (W_s @ h_{l-1}) + (b_s + p_bias)),  h_{-1} = 0
// Block: 4 sequences, 512 threads. Thread t: row r = t>>1, half hf = t&1 holds
// W_s[r][hf*128 .. +128) in VGPRs. h double-buffered in LDS; 1 barrier/step.
// accum[B][H][W][C] = sum over directions (dir0 writes, others read-add-write).
// ---------------------------------------------------------------------------
__global__ __launch_bounds__(512) void k_scan(const float* __restrict__ proj,
                                              const float* __restrict__ conf,
                                              const float* __restrict__ Ws,
                                              const float* __restrict__ b_s,
                                              const float* __restrict__ p_bias,
                                              float* __restrict__ accum,
                                              int vertical, int rev, int first) {
  __shared__ __align__(16) float hbuf[2][4][CC];   // 8 KiB
  const int t = threadIdx.x;
  const int r = t >> 1;
  const int hf = t & 1;
  const int s0 = blockIdx.x * 4;

  // weights into registers (512B contiguous per thread, L2-resident)
  float Wreg[128];
  {
    const float* wrow = Ws + r * CC + hf * 128;
#pragma unroll
    for (int j4 = 0; j4 < 32; ++j4) {
      float4 v = *reinterpret_cast<const float4*>(wrow + j4 * 4);
      Wreg[j4 * 4 + 0] = v.x; Wreg[j4 * 4 + 1] = v.y;
      Wreg[j4 * 4 + 2] = v.z; Wreg[j4 * 4 + 3] = v.w;
    }
  }
  const float cst = b_s[r] + p_bias[r];

  if (t < 256) {
    hbuf[0][0][t] = 0.f; hbuf[0][1][t] = 0.f; hbuf[0][2][t] = 0.f; hbuf[0][3][t] = 0.f;
  }

  const int dp = rev ? -CC : CC;
  const int dc = vertical ? (rev ? -WW : WW) : (rev ? -1 : 1);
  const int da = vertical ? (rev ? -(WW * CC) : (WW * CC)) : dp;
  const int pstart = rev ? 127 : 0;

  int pix[4], cix[4], aix[4];
#pragma unroll
  for (int s = 0; s < 4; ++s) {
    int n = s0 + s;
    if (!vertical) {
      pix[s] = (n * WW + pstart) * CC + r;
      cix[s] = n * WW + pstart;
      aix[s] = pix[s];
    } else {
      int b = n >> 7, wc = n & 127;
      pix[s] = (n * HH + pstart) * CC + r;
      cix[s] = b * HW + pstart * WW + wc;
      aix[s] = (b * HW + pstart * WW + wc) * CC + r;
    }
  }

  float pj[4], gg[4];
  if (!hf) {
#pragma unroll
    for (int s = 0; s < 4; ++s) {
      pj[s] = proj[pix[s]]; gg[s] = conf[cix[s]];
      pix[s] += dp; cix[s] += dc;
    }
  }
  __syncthreads();

  for (int k = 0; k < 128; ++k) {
    float pjn[4], ggn[4], ard[4];
    if (!hf) {
      if (k < 127) {
#pragma unroll
        for (int s = 0; s < 4; ++s) { pjn[s] = proj[pix[s]]; ggn[s] = conf[cix[s]]; }
      }
      if (!first) {
#pragma unroll
        for (int s = 0; s < 4; ++s) ard[s] = accum[aix[s]];
      }
    }

    float dt[4] = {0.f, 0.f, 0.f, 0.f};
    const float* hb = &hbuf[k & 1][0][0] + hf * 128;
#pragma unroll
    for (int j4 = 0; j4 < 32; ++j4) {
      const float w0 = Wreg[j4 * 4 + 0], w1 = Wreg[j4 * 4 + 1];
      const float w2 = Wreg[j4 * 4 + 2], w3 = Wreg[j4 * 4 + 3];
#pragma unroll
      for (int s = 0; s < 4; ++s) {
        float4 hv = *reinterpret_cast<const float4*>(hb + s * CC + j4 * 4);
        dt[s] += w0 * hv.x + w1 * hv.y + w2 * hv.z + w3 * hv.w;
      }
    }
#pragma unroll
    for (int s = 0; s < 4; ++s) dt[s] += __shfl_xor(dt[s], 1);

    if (!hf) {
#pragma unroll
      for (int s = 0; s < 4; ++s) {
        float hn = fmaxf(pj[s] + gg[s] * dt[s] + cst, 0.f);
        hbuf[(k + 1) & 1][s][r] = hn;
        accum[aix[s]] = first ? hn : (hn + ard[s]);
        aix[s] += da;
      }
#pragma unroll
      for (int s = 0; s < 4; ++s) {
        pj[s] = pjn[s]; gg[s] = ggn[s];
        pix[s] += dp; cix[s] += dc;
      }
    }
    __syncthreads();
  }
}

// ---------------------------------------------------------------------------
// z = out_w @ fused + out_b + feature ; write z to out (channel-first),
// accumulate GroupNorm partial sums per (b, group).
// ---------------------------------------------------------------------------
__global__ __launch_bounds__(256) void k_out_gemm(const float* __restrict__ fused,
                                                  const float* __restrict__ owT,
                                                  const float* __restrict__ out_b,
                                                  const float* __restrict__ feature,
                                                  float* __restrict__ out,
                                                  float* __restrict__ stats) {
  __shared__ float Fs[64 * 256];   // [c][px]
  const int t = threadIdx.x;
  const int b = blockIdx.y;
  const int p0 = blockIdx.x * 64;

  // stage fused tile (layout [px][C] in global) transposed into [c][px]
  {
    const int px = t >> 2, cq = t & 3;
    const float* src = fused + ((b * HW + p0 + px) * 256 + cq * 64);
#pragma unroll
    for (int kk = 0; kk < 16; ++kk) {
      float4 v = *reinterpret_cast<const float4*>(src + kk * 4);   // fully coalesced
      int c = cq * 64 + kk * 4;
      Fs[(c + 0) * 64 + px] = v.x; Fs[(c + 1) * 64 + px] = v.y;
      Fs[(c + 2) * 64 + px] = v.z; Fs[(c + 3) * 64 + px] = v.w;
    }
  }
  __syncthreads();

  const int d = t;
  float acc[64];
#pragma unroll
  for (int i = 0; i < 64; ++i) acc[i] = 0.f;

#pragma unroll 4
  for (int c = 0; c < 256; ++c) {
    float w = owT[c * 256 + d];
#pragma unroll
    for (int p4 = 0; p4 < 16; ++p4) {
      float4 xv = *reinterpret_cast<const float4*>(&Fs[c * 64 + p4 * 4]);
      acc[p4 * 4 + 0] += w * xv.x;
      acc[p4 * 4 + 1] += w * xv.y;
      acc[p4 * 4 + 2] += w * xv.z;
      acc[p4 * 4 + 3] += w * xv.w;
    }
  }

  const float bia = out_b[d];
  const int obase = ((b * 256 + d) << 14) + p0;
  const float* fsrc = feature + obase;
  float s1 = 0.f, s2 = 0.f;
#pragma unroll
  for (int j = 0; j < 64; ++j) {
    float z = acc[j] + bia + fsrc[j];
    out[obase + j] = z;
    s1 += z; s2 += z * z;
  }
  // reduce across the 8 channels of a GN group (adjacent lanes)
  s1 += __shfl_xor(s1, 1); s2 += __shfl_xor(s2, 1);
  s1 += __shfl_xor(s1, 2); s2 += __shfl_xor(s2, 2);
  s1 += __shfl_xor(s1, 4); s2 += __shfl_xor(s2, 4);
  if ((d & 7) == 0) {
    int g = d >> 3;
    atomicAdd(&stats[(b * 32 + g) * 2 + 0], s1);
    atomicAdd(&stats[(b * 32 + g) * 2 + 1], s2);
  }
}

// ---------------------------------------------------------------------------
// In-place GroupNorm normalize of d_out using accumulated stats.
// ---------------------------------------------------------------------------
__global__ __launch_bounds__(256) void k_norm(float* __restrict__ out,
                                              const float* __restrict__ stats,
                                              const float* __restrict__ gn_w,
                                              const float* __restrict__ gn_b) {
  const int i = (blockIdx.x * 256 + threadIdx.x) << 2;
  const int c = (i >> 14) & 255;
  const int b = i >> 22;
  const int g = c >> 3;
  float s1 = stats[(b * 32 + g) * 2 + 0];
  float s2 = stats[(b * 32 + g) * 2 + 1];
  const float invN = 1.f / 131072.f;
  float mu = s1 * invN;
  float var = fmaxf(s2 * invN - mu * mu, 0.f);
  float is = rsqrtf(var + 1e-5f);
  float wmul = gn_w[c] * is;
  float badd = gn_b[c] - mu * wmul;
  float4 z = *reinterpret_cast<float4*>(&out[i]);
  z.x = z.x * wmul + badd; z.y = z.y * wmul + badd;
  z.z = z.z * wmul + badd; z.w = z.w * wmul + badd;
  *reinterpret_cast<float4*>(&out[i]) = z;
}

// ---------------------------------------------------------------------------
extern "C" void kernel_launch(void* const* d_in, const int* in_sizes, int n_in,
                              void* d_out, int out_size, void* d_ws, size_t ws_size,
                              hipStream_t stream) {
  const float* feature = (const float*)d_in[0];
  const float* blog    = (const float*)d_in[1];
  const float* beta    = (const float*)d_in[2];
  const float* W_in    = (const float*)d_in[3];
  const float* b_in    = (const float*)d_in[4];
  const float* W_s     = (const float*)d_in[5];
  const float* b_s     = (const float*)d_in[6];
  const float* p_bias  = (const float*)d_in[7];
  const float* out_w   = (const float*)d_in[8];
  const float* out_b   = (const float*)d_in[9];
  const float* gn_w    = (const float*)d_in[10];
  const float* gn_b    = (const float*)d_in[11];
  float* out = (float*)d_out;

  // workspace layout (floats): proj 33.5M | accum 33.5M | conf 128K | stats 512 | wT 320K
  float* ws    = (float*)d_ws;
  float* proj  = ws;
  float* accum = ws + 33554432;
  float* conf  = ws + 67108864;
  float* stats = ws + 67239936;
  float* wT    = ws + 67240448;    // 5 * 65536

  k_conf<<<NPIX / 256, 256, 0, stream>>>(blog, beta, conf, stats);
  k_tr<<<(5 * 65536) / 256, 256, 0, stream>>>(W_in, out_w, wT);

  for (int dir = 0; dir < 4; ++dir) {
    const int vertical = (dir >= 2);
    const int rev = (dir == 1 || dir == 3);
    k_proj_gemm<<<dim3(HW / 64, BB), 256, 0, stream>>>(
        feature, wT + dir * 65536, b_in + dir * 256, proj, vertical);
    k_scan<<<256, 512, 0, stream>>>(
        proj, conf, W_s + dir * 65536, b_s + dir * 256, p_bias + dir * 256,
        accum, vertical, rev, dir == 0);
  }

  k_out_gemm<<<dim3(HW / 64, BB), 256, 0, stream>>>(
      accum, wT + 4 * 65536, out_b, feature, out, stats);
  k_norm<<<(BB * CC * HW) / 1024, 256, 0, stream>>>(out, stats, gn_w, gn_b);
}